// Round 9
// baseline (456.385 us; speedup 1.0000x reference)
//
#include <hip/hip_runtime.h>
#include <math.h>

typedef unsigned short u16;
typedef short s16x8 __attribute__((ext_vector_type(8)));
typedef float f32x4 __attribute__((ext_vector_type(4)));
typedef long long ll;

__device__ inline u16 f2bf(float f) {
    unsigned u = __float_as_uint(f);
    u += 0x7fffu + ((u >> 16) & 1u);
    return (u16)(u >> 16);
}
__device__ inline float bf2f(u16 h) { return __uint_as_float(((unsigned)h) << 16); }

// async global->LDS, 16B per lane; LDS dest = wave-uniform base + lane*16
__device__ __forceinline__ void glds16(const u16* g, u16* l) {
    __builtin_amdgcn_global_load_lds(
        (__attribute__((address_space(1))) void*)(void*)g,
        (__attribute__((address_space(3))) void*)l, 16, 0, 0);
}

// ---------------- LayerNorm -> bf16 (one block per row, D=1024) ----------------
__global__ __launch_bounds__(256) void ln_bf16(const float* __restrict__ x,
                                               const float* __restrict__ g,
                                               const float* __restrict__ b,
                                               u16* __restrict__ out, int D) {
    int row = blockIdx.x;
    const float* xr = x + (size_t)row * D;
    int t = threadIdx.x;
    float4 v = ((const float4*)xr)[t];
    float s = v.x + v.y + v.z + v.w;
    __shared__ float sm[4];
    #pragma unroll
    for (int o = 32; o > 0; o >>= 1) s += __shfl_down(s, o, 64);
    int lane = t & 63, wv = t >> 6;
    if (lane == 0) sm[wv] = s;
    __syncthreads();
    float mean = (sm[0] + sm[1] + sm[2] + sm[3]) * (1.0f / 1024.0f);
    float dx = v.x - mean, dy = v.y - mean, dz = v.z - mean, dw = v.w - mean;
    float s2 = dx * dx + dy * dy + dz * dz + dw * dw;
    __syncthreads();
    #pragma unroll
    for (int o = 32; o > 0; o >>= 1) s2 += __shfl_down(s2, o, 64);
    if (lane == 0) sm[wv] = s2;
    __syncthreads();
    float var = (sm[0] + sm[1] + sm[2] + sm[3]) * (1.0f / 1024.0f);
    float rstd = rsqrtf(var + 1e-5f);
    float4 gg = ((const float4*)g)[t], bb = ((const float4*)b)[t];
    ushort4 o4;
    o4.x = f2bf(dx * rstd * gg.x + bb.x);
    o4.y = f2bf(dy * rstd * gg.y + bb.y);
    o4.z = f2bf(dz * rstd * gg.z + bb.z);
    o4.w = f2bf(dw * rstd * gg.w + bb.w);
    ((ushort4*)(out + (size_t)row * D))[t] = o4;
}

// ---------------- combine split-K parts + residual + bias, then LayerNorm ----------------
__global__ __launch_bounds__(256) void combine_ln(
    const float* __restrict__ x, const float* __restrict__ p0,
    const float* __restrict__ p1, const float* __restrict__ ob,
    const float* __restrict__ g, const float* __restrict__ b,
    float* __restrict__ x2, u16* __restrict__ xn2) {
    int row = blockIdx.x;
    int t = threadIdx.x;
    size_t base = (size_t)row * 256;  // float4 units
    float4 v = ((const float4*)x)[base + t];
    float4 a0 = ((const float4*)p0)[base + t];
    float4 a1 = ((const float4*)p1)[base + t];
    float4 ob4 = ((const float4*)ob)[t];
    v.x += a0.x + a1.x + ob4.x;
    v.y += a0.y + a1.y + ob4.y;
    v.z += a0.z + a1.z + ob4.z;
    v.w += a0.w + a1.w + ob4.w;
    ((float4*)x2)[base + t] = v;
    float s = v.x + v.y + v.z + v.w;
    __shared__ float sm[4];
    #pragma unroll
    for (int o = 32; o > 0; o >>= 1) s += __shfl_down(s, o, 64);
    int lane = t & 63, wv = t >> 6;
    if (lane == 0) sm[wv] = s;
    __syncthreads();
    float mean = (sm[0] + sm[1] + sm[2] + sm[3]) * (1.0f / 1024.0f);
    float dx = v.x - mean, dy = v.y - mean, dz = v.z - mean, dw = v.w - mean;
    float s2 = dx * dx + dy * dy + dz * dz + dw * dw;
    __syncthreads();
    #pragma unroll
    for (int o = 32; o > 0; o >>= 1) s2 += __shfl_down(s2, o, 64);
    if (lane == 0) sm[wv] = s2;
    __syncthreads();
    float var = (sm[0] + sm[1] + sm[2] + sm[3]) * (1.0f / 1024.0f);
    float rstd = rsqrtf(var + 1e-5f);
    float4 gg = ((const float4*)g)[t], bb = ((const float4*)b)[t];
    ushort4 o4;
    o4.x = f2bf(dx * rstd * gg.x + bb.x);
    o4.y = f2bf(dy * rstd * gg.y + bb.y);
    o4.z = f2bf(dz * rstd * gg.z + bb.z);
    o4.w = f2bf(dw * rstd * gg.w + bb.w);
    ((ushort4*)(xn2 + (size_t)row * 1024))[t] = o4;
}

// out = x2 + p0 + p1 + b2
__global__ __launch_bounds__(256) void combine_out(
    const float* __restrict__ x2, const float* __restrict__ p0,
    const float* __restrict__ p1, const float* __restrict__ b2,
    float* __restrict__ out) {
    size_t i = (size_t)blockIdx.x * 256 + threadIdx.x;
    int col4 = (int)(i & 255);
    float4 v = ((const float4*)x2)[i];
    float4 a0 = ((const float4*)p0)[i];
    float4 a1 = ((const float4*)p1)[i];
    float4 bb = ((const float4*)b2)[col4];
    v.x += a0.x + a1.x + bb.x;
    v.y += a0.y + a1.y + bb.y;
    v.z += a0.z + a1.z + bb.z;
    v.w += a0.w + a1.w + bb.w;
    ((float4*)out)[i] = v;
}

// ---------------- prep: pack q_b,k_b,v_b -> bcat[3E]; zero den[BN] ----------------
__global__ void prep(const float* __restrict__ qb, const float* __restrict__ kb,
                     const float* __restrict__ vb, float* __restrict__ bcat,
                     float* __restrict__ den, int E, int BN) {
    int i = blockIdx.x * 256 + threadIdx.x;
    if (i < E) {
        bcat[i] = qb[i];
        bcat[E + i] = kb[i];
        bcat[2 * E + i] = vb[i];
    }
    if (i < BN) den[i] = 0.f;
}

// ---------------- all 6 weight transposes in one dispatch ----------------
__global__ __launch_bounds__(256) void transpose_all(
    const float* __restrict__ q_w, const float* __restrict__ k_w,
    const float* __restrict__ v_w, const float* __restrict__ o_w,
    const float* __restrict__ w1, const float* __restrict__ w2,
    u16* __restrict__ qkvT, u16* __restrict__ oT,
    u16* __restrict__ w1T, u16* __restrict__ w2T) {
    int z = blockIdx.y;
    const float* src;
    u16* dst;
    int R, C, tprLog;  // tiles-per-row = C/32, log2
    switch (z) {
        case 0: src = q_w; dst = qkvT;                           R = 1024; C = 2048; tprLog = 6; break;
        case 1: src = k_w; dst = qkvT + (size_t)2 * 1024 * 1024; R = 1024; C = 2048; tprLog = 6; break;
        case 2: src = v_w; dst = qkvT + (size_t)4 * 1024 * 1024; R = 1024; C = 2048; tprLog = 6; break;
        case 3: src = o_w; dst = oT;                             R = 2048; C = 1024; tprLog = 5; break;
        case 4: src = w1;  dst = w1T;                            R = 1024; C = 4096; tprLog = 7; break;
        default: src = w2; dst = w2T;                            R = 4096; C = 1024; tprLog = 5; break;
    }
    int bx = blockIdx.x;
    int ntiles = (R >> 5) << (tprLog);
    if (bx >= ntiles) return;
    int c0 = (bx & ((1 << tprLog) - 1)) * 32;
    int r0 = (bx >> tprLog) * 32;
    __shared__ u16 tile[32][33];
    int tx = threadIdx.x & 31, ty = threadIdx.x >> 5;
    #pragma unroll
    for (int i = 0; i < 32; i += 8)
        tile[ty + i][tx] = f2bf(src[(size_t)(r0 + ty + i) * C + c0 + tx]);
    __syncthreads();
    #pragma unroll
    for (int i = 0; i < 32; i += 8)
        dst[(size_t)(c0 + ty + i) * R + r0 + tx] = tile[tx][ty + i];
}

// generic bf16 transpose (used for V^T): in [R,C] (row stride ldIn) -> out [C,R]
__global__ __launch_bounds__(256) void transpose_u16(const u16* __restrict__ in,
                                                     u16* __restrict__ out,
                                                     int R, int C, int ldIn,
                                                     ll sIn, ll sOut) {
    in += (size_t)blockIdx.z * sIn;
    out += (size_t)blockIdx.z * sOut;
    __shared__ u16 tile[32][33];
    int tx = threadIdx.x & 31, ty = threadIdx.x >> 5;
    int c0 = blockIdx.x * 32, r0 = blockIdx.y * 32;
    #pragma unroll
    for (int i = 0; i < 32; i += 8)
        tile[ty + i][tx] = in[(size_t)(r0 + ty + i) * ldIn + c0 + tx];
    __syncthreads();
    #pragma unroll
    for (int i = 0; i < 32; i += 8)
        out[(size_t)(c0 + ty + i) * R + r0 + tx] = tile[tx][ty + i];
}

// ---------------- GEMM NT (128x128, 2-barrier) -- kept for TRIL/DIV ----------------
enum { EPI_QKV = 0, EPI_TRIL = 2, EPI_DIV = 3, EPI_GELU = 5, EPI_PART = 6 };

#define TM 128
#define TN 128

template <int EPI, int BKt>
__global__ __launch_bounds__(256) void gemm_nt(
    const u16* __restrict__ A, const u16* __restrict__ B, void* __restrict__ Cv,
    const float* __restrict__ bias, float* __restrict__ den,
    int M, int N, int K, int lda, int ldb,
    ll sA, ll sB, ll sC, ll sAux) {
    int z = blockIdx.z;
    A += (size_t)z * sA;
    B += (size_t)z * sB;

    int p = blockIdx.y * gridDim.x + blockIdx.x;
    int m0, n0;
    if (EPI == EPI_TRIL || EPI == EPI_DIV) {
        int nb = gridDim.x;
        int panel = nb * 4;
        int pp = p / panel, rr = p - pp * panel;
        m0 = (pp * 4 + (rr & 3)) * TM;
        n0 = (rr >> 2) * TN;
    } else {
        int g = p & 7, r = p >> 3;
        int lw = gridDim.x >> 2, lh = gridDim.y >> 1;
        int ly = r / lw, lx = r - ly * lw;
        m0 = ((g >> 2) * lh + ly) * TM;
        n0 = ((g & 3) * lw + lx) * TN;
    }

    int t = threadIdx.x;

    if (EPI == EPI_TRIL && n0 > m0 + (TM - 1)) {
        u16* C = (u16*)Cv + (size_t)z * sC;
        #pragma unroll
        for (int s = 0; s < 8; ++s) {
            int v = t + 256 * s;
            int row = v >> 4, cf = (v & 15) * 8;
            *(uint4*)&C[(size_t)(m0 + row) * N + n0 + cf] = make_uint4(0, 0, 0, 0);
        }
        return;
    }

    __shared__ __align__(16) u16 As[TM * BKt];
    __shared__ __align__(16) u16 Bs[TN * BKt];

    f32x4 acc[4][4];
    #pragma unroll
    for (int i = 0; i < 4; i++)
        #pragma unroll
        for (int j = 0; j < 4; j++) { f32x4 zz = {0.f, 0.f, 0.f, 0.f}; acc[i][j] = zz; }

    int kend = (EPI == EPI_DIV) ? (m0 + TM < K ? m0 + TM : K) : K;

    int lane = t & 63, wv = t >> 6;
    int lr = lane & 15, q = lane >> 4;
    int wm = (wv & 1) * 64, wn = (wv >> 1) * 64;

    u16* lA = As + wv * 32 * BKt;
    u16* lB = Bs + wv * 32 * BKt;

    int srow, skf;
    if (BKt == 32) {
        srow = wv * 32 + (lane >> 2);
        skf = (((lane & 3) - ((lane >> 3) & 3)) & 3) * 8;
    } else {
        srow = wv * 32 + (lane >> 3);
        skf = (((lane & 7) - (lane >> 3)) & 7) * 8;
    }
    const u16* gA0 = A + (size_t)(m0 + srow) * lda + skf;
    const u16* gB0 = B + (size_t)(n0 + srow) * ldb + skf;

    int ca[2][4], cb[2][4];
    #pragma unroll
    for (int i = 0; i < 4; i++) {
        int ra = wm + i * 16 + lr;
        int rb = wn + i * 16 + lr;
        if (BKt == 32) {
            ca[0][i] = (ra * 4 + ((q + (ra >> 1)) & 3)) * 8;
            cb[0][i] = (rb * 4 + ((q + (rb >> 1)) & 3)) * 8;
        } else {
            ca[0][i] = (ra * 8 + ((q + (ra & 7)) & 7)) * 8;
            ca[1][i] = (ra * 8 + ((4 + q + (ra & 7)) & 7)) * 8;
            cb[0][i] = (rb * 8 + ((q + (rb & 7)) & 7)) * 8;
            cb[1][i] = (rb * 8 + ((4 + q + (rb & 7)) & 7)) * 8;
        }
    }

    for (int k0 = 0; k0 < kend; k0 += BKt) {
        if (BKt == 32) {
            glds16(gA0 + k0, lA);
            glds16(gA0 + k0 + (size_t)16 * lda, lA + 16 * BKt);
            glds16(gB0 + k0, lB);
            glds16(gB0 + k0 + (size_t)16 * ldb, lB + 16 * BKt);
        } else {
            #pragma unroll
            for (int r = 0; r < 4; ++r) {
                glds16(gA0 + k0 + (size_t)(8 * r) * lda, lA + r * 8 * BKt);
                glds16(gB0 + k0 + (size_t)(8 * r) * ldb, lB + r * 8 * BKt);
            }
        }
        __syncthreads();
        #pragma unroll
        for (int kk = 0; kk < BKt / 32; ++kk) {
            s16x8 af[4], bfr[4];
            #pragma unroll
            for (int i = 0; i < 4; i++) af[i] = *(const s16x8*)&As[ca[kk][i]];
            #pragma unroll
            for (int j = 0; j < 4; j++) bfr[j] = *(const s16x8*)&Bs[cb[kk][j]];
            #pragma unroll
            for (int i = 0; i < 4; i++)
                #pragma unroll
                for (int j = 0; j < 4; j++)
                    acc[i][j] = __builtin_amdgcn_mfma_f32_16x16x32_bf16(af[i], bfr[j], acc[i][j], 0, 0, 0);
        }
        __syncthreads();
    }

    u16* Cb = (u16*)Cv + (size_t)z * sC;
    float* Cf = (float*)Cv + (size_t)z * sC;
    bool isQK = (EPI == EPI_QKV) && (n0 < 4096);
    #pragma unroll
    for (int i = 0; i < 4; i++) {
        #pragma unroll
        for (int r = 0; r < 4; r++) {
            int row = m0 + wm + i * 16 + q * 4 + r;
            float rs = 0.f;
            #pragma unroll
            for (int j = 0; j < 4; j++) {
                int col = n0 + wn + j * 16 + lr;
                float v = acc[i][j][r];
                if (EPI == EPI_QKV) {
                    v += bias[col];
                    if (isQK) v = (v > 0.f) ? (v + 1.f) : __expf(v);
                    Cb[(size_t)row * N + col] = f2bf(v);
                } else if (EPI == EPI_TRIL) {
                    v = (col <= row) ? v : 0.f;
                    rs += v;
                    Cb[(size_t)row * N + col] = f2bf(v);
                } else if (EPI == EPI_DIV) {
                    float d = den[(size_t)z * sAux + row] + 1e-6f;
                    Cb[(size_t)row * N + col] = f2bf(v / d);
                } else if (EPI == EPI_GELU) {
                    v += bias[col];
                    float u = v * (0.7978845608f + 0.0356774081f * v * v);
                    u = fminf(u, 40.f);
                    float e = __expf(2.f * u);
                    v = v * __fdividef(e, e + 1.f);
                    Cb[(size_t)row * N + col] = f2bf(v);
                } else if (EPI == EPI_PART) {
                    Cf[(size_t)row * N + col] = v;
                }
            }
            if (EPI == EPI_TRIL) {
                #pragma unroll
                for (int m = 1; m < 16; m <<= 1) rs += __shfl_xor(rs, m, 16);
                if (lr == 0) atomicAdd(&den[(size_t)z * sAux + row], rs);
            }
        }
    }
}

// ---------------- GEMM NT 128xTNt, 4-wave, BK=32, 3-buf counted-vmcnt ----------------
// TNt=256: wave tile 64x128, LDS 72KB -> 2 blocks/CU (QKV/GELU; R8-proven:
//   0 bank conflicts, coalesced, 70us QKV).
// TNt=128: wave tile 64x64, LDS 48KB -> 3 blocks/CU capacity (PART split-K:
//   512 blocks all co-resident ~2/CU; higher TLP for short-K splits).
// Layout: row-major + 16B-chunk XOR swizzle at row-pair granularity:
//   staging row = lane>>2 (coalesced 64B/quad), source chunk pre-swizzled
//   ((lane&3)-((lane>>3)&3))&3 so linear LDS dest stores chunk'=(c+(row>>1))&3;
//   frag read chunk' = (q+(lr>>1))&3 -> 2 lanes/bank-quad = free (m136).
// Schedule: 2-phase / 3-buffer; stage t+2 during t; end-of-tile counted vmcnt
//   (6 for TNt=256: 2A+4B loads/tile; 4 for TNt=128: 2A+2B) drains t+1 exactly;
//   no forced lgkmcnt (compiler fine-grains; MFMA overlaps LDS drain).
// EPI_PART: split-K via blockIdx.z (A,B advance z*K along rows; C fp32 += z*sC).
// Grid MUST be (N/TNt, M/128[, z]) with gridDim.x%4==0, gridDim.y%2==0.
template <int EPI, int TNt>
__global__ __launch_bounds__(256, 2) void gemm2b(
    const u16* __restrict__ A, const u16* __restrict__ B, void* __restrict__ Cv,
    const float* __restrict__ bias, int M, int N, int K, int lda, int ldb, ll sC) {

    constexpr int NJ = TNt / 32;          // B frags per wave (8 or 4)
    constexpr int BUF = 4096 + TNt * 32;  // u16 per buffer
    __shared__ __align__(16) u16 lds[3][BUF];

    int z = blockIdx.z;
    A += (size_t)z * K;   // split-K: advance along row (lda = full stride)
    B += (size_t)z * K;

    int p = blockIdx.y * gridDim.x + blockIdx.x;
    int g = p & 7, rr = p >> 3;
    int lw = gridDim.x >> 2, lh = gridDim.y >> 1;
    int ly = rr / lw, lx = rr - ly * lw;
    int m0 = ((g >> 2) * lh + ly) * 128;
    int n0 = ((g & 3) * lw + lx) * TNt;

    int t = threadIdx.x;
    int lane = t & 63, wid = t >> 6;  // 4 waves
    int lr = lane & 15, q = lane >> 4;

    // staging: row = lane>>2 (coalesced 64B per quad-lane), pre-swizzled chunk
    int skf = (((lane & 3) - ((lane >> 3) & 3)) & 3) * 8;
    const u16* gA = A + (size_t)(m0 + wid * 32 + (lane >> 2)) * lda + skf;
    const u16* gB = B + (size_t)(n0 + wid * (TNt / 4) + (lane >> 2)) * ldb + skf;
    int sdA = wid * 1024;                  // wave's 32 A-rows
    int sdB = 4096 + wid * (TNt * 32 / 4); // wave's TNt/4 B-rows

    int nk = K >> 5;

    auto stageA = [&](int tt, int d) {
        int kt = (tt < nk ? tt : nk - 1) << 5;
        glds16(gA + kt, &lds[d][sdA]);
        glds16(gA + kt + (size_t)16 * lda, &lds[d][sdA + 512]);
    };
    auto stageB = [&](int tt, int d) {
        int kt = (tt < nk ? tt : nk - 1) << 5;
        #pragma unroll
        for (int r2 = 0; r2 < TNt / 64; ++r2)
            glds16(gB + kt + (size_t)(16 * r2) * ldb, &lds[d][sdB + r2 * 512]);
    };

    f32x4 acc[4][NJ];
    #pragma unroll
    for (int i = 0; i < 4; i++)
        #pragma unroll
        for (int j = 0; j < NJ; j++) { f32x4 zz = {0.f, 0.f, 0.f, 0.f}; acc[i][j] = zz; }

    int wm = (wid & 1) * 64, wn = (wid >> 1) * (TNt / 2);
    // swizzled frag offsets (u16): row*32 + ((q + (lr>>1))&3)*8; frag i/j adds 512
    int csw = ((q + (lr >> 1)) & 3) * 8;
    int aoff = (wm + lr) * 32 + csw;
    int boff = 4096 + (wn + lr) * 32 + csw;

    // ---- prologue: tiles 0,1 staged ----
    stageA(0, 0); stageB(0, 0);
    stageA(1, 1); stageB(1, 1);
    if constexpr (TNt == 256) asm volatile("s_waitcnt vmcnt(6)" ::: "memory");
    else                      asm volatile("s_waitcnt vmcnt(4)" ::: "memory");
    asm volatile("s_barrier" ::: "memory");

    s16x8 af[4], bf_[NJ];

    int cur = 0;
    for (int tt = 0; tt < nk; ++tt) {
        int nx2 = cur + 2; if (nx2 >= 3) nx2 -= 3;
        const u16* L = &lds[cur][0];

        // ---- phase 1: ds B(j<NJ/2) + A(all) | stage B(t+2) | mfma j<NJ/2 ----
        #pragma unroll
        for (int j = 0; j < NJ / 2; j++) bf_[j] = *(const s16x8*)&L[boff + j * 512];
        #pragma unroll
        for (int i = 0; i < 4; i++) af[i] = *(const s16x8*)&L[aoff + i * 512];
        stageB(tt + 2, nx2);
        asm volatile("s_barrier" ::: "memory");
        __builtin_amdgcn_s_setprio(1);
        #pragma unroll
        for (int i = 0; i < 4; i++)
            #pragma unroll
            for (int j = 0; j < NJ / 2; j++)
                acc[i][j] = __builtin_amdgcn_mfma_f32_16x16x32_bf16(af[i], bf_[j], acc[i][j], 0, 0, 0);
        __builtin_amdgcn_s_setprio(0);
        asm volatile("s_barrier" ::: "memory");

        // ---- phase 2: ds B(j>=NJ/2) | stage A(t+2) | mfma j>=NJ/2 | vmcnt ----
        #pragma unroll
        for (int j = NJ / 2; j < NJ; j++) bf_[j] = *(const s16x8*)&L[boff + j * 512];
        stageA(tt + 2, nx2);
        asm volatile("s_barrier" ::: "memory");
        __builtin_amdgcn_s_setprio(1);
        #pragma unroll
        for (int i = 0; i < 4; i++)
            #pragma unroll
            for (int j = NJ / 2; j < NJ; j++)
                acc[i][j] = __builtin_amdgcn_mfma_f32_16x16x32_bf16(af[i], bf_[j], acc[i][j], 0, 0, 0);
        __builtin_amdgcn_s_setprio(0);
        if constexpr (TNt == 256) asm volatile("s_waitcnt vmcnt(6)" ::: "memory");  // t+1 landed; never 0
        else                      asm volatile("s_waitcnt vmcnt(4)" ::: "memory");
        asm volatile("s_barrier" ::: "memory");

        cur = cur + 1; if (cur >= 3) cur -= 3;
    }

    asm volatile("s_waitcnt vmcnt(0)" ::: "memory");  // drain DMA before LDS dealloc

    // ---- epilogue ----
    u16* Cb = (u16*)Cv;
    float* Cf = (float*)Cv + (size_t)z * sC;
    #pragma unroll
    for (int i = 0; i < 4; i++) {
        #pragma unroll
        for (int r = 0; r < 4; r++) {
            int row = m0 + wm + i * 16 + q * 4 + r;
            #pragma unroll
            for (int j = 0; j < NJ; j++) {
                int col = n0 + wn + j * 16 + lr;
                if (EPI == EPI_PART) {
                    Cf[(size_t)row * N + col] = acc[i][j][r];
                } else {
                    float v = acc[i][j][r] + bias[col];
                    if (EPI == EPI_QKV) {
                        if (n0 + wn + j * 16 < 4096) v = (v > 0.f) ? (v + 1.f) : __expf(v);  // elu+1
                    } else {  // EPI_GELU
                        float u = v * (0.7978845608f + 0.0356774081f * v * v);
                        u = fminf(u, 40.f);
                        float e = __expf(2.f * u);
                        v = v * __fdividef(e, e + 1.f);
                    }
                    Cb[(size_t)row * N + col] = f2bf(v);
                }
            }
        }
    }
}

extern "C" void kernel_launch(void* const* d_in, const int* in_sizes, int n_in,
                              void* d_out, int out_size, void* d_ws, size_t ws_size,
                              hipStream_t stream) {
    const float* x    = (const float*)d_in[0];
    const float* q_w  = (const float*)d_in[1];
    const float* q_b  = (const float*)d_in[2];
    const float* k_w  = (const float*)d_in[3];
    const float* k_b  = (const float*)d_in[4];
    const float* v_w  = (const float*)d_in[5];
    const float* v_b  = (const float*)d_in[6];
    const float* o_w  = (const float*)d_in[7];
    const float* o_b  = (const float*)d_in[8];
    const float* ln1g = (const float*)d_in[9];
    const float* ln1b = (const float*)d_in[10];
    const float* ln2g = (const float*)d_in[11];
    const float* ln2b = (const float*)d_in[12];
    const float* w1   = (const float*)d_in[13];
    const float* b1   = (const float*)d_in[14];
    const float* w2   = (const float*)d_in[15];
    const float* b2   = (const float*)d_in[16];
    float* out = (float*)d_out;

    constexpr int Bb = 2, N = 2048, D = 1024, E = 2048, F = 4096;
    constexpr int BN = Bb * N;     // 4096
    constexpr int E3 = 3 * E;      // 6144

    char* ws = (char*)d_ws;
    size_t off = 0;
    auto alloc = [&](size_t bytes) -> void* {
        void* p = ws + off;
        off += (bytes + 255) & ~(size_t)255;
        return p;
    };
    u16*   qkvT = (u16*)alloc((size_t)E3 * D * 2);     // 12 MB
    u16*   oT   = (u16*)alloc((size_t)D * E * 2);      // 4 MB
    u16*   w1T  = (u16*)alloc((size_t)F * D * 2);      // 8 MB
    u16*   w2T  = (u16*)alloc((size_t)D * F * 2);      // 8 MB
    float* bcat = (float*)alloc((size_t)E3 * 4);
    u16*   xn   = (u16*)alloc((size_t)BN * D * 2);     // 8 MB (reused as xn2)
    u16*   QKV  = (u16*)alloc((size_t)BN * E3 * 2);    // 48 MB (reused: P, h)
    u16*   Vt   = (u16*)alloc((size_t)Bb * E * N * 2); // 16 MB (reused as x2 fp32)
    u16*   Amat = (u16*)alloc((size_t)Bb * N * N * 2); // 32 MB (reused as parts)
    float* den  = (float*)alloc((size_t)BN * 4);

    u16*   xn2 = xn;
    u16*   P   = QKV;                  // [BN,E] bf16
    u16*   h   = QKV + (size_t)8 * 1024 * 1024;  // [BN,F] bf16
    float* x2  = (float*)Vt;           // [BN,D] fp32
    float* pt0 = (float*)Amat;         // split-K partial 0
    float* pt1 = pt0 + (size_t)BN * D; // split-K partial 1

    dim3 blk(256);

    // ---- prep: biases + den zero ----
    prep<<<dim3((BN + 255) / 256), blk, 0, stream>>>(q_b, k_b, v_b, bcat, den, E, BN);

    // ---- all weight transposes, one dispatch ----
    transpose_all<<<dim3(4096, 6), blk, 0, stream>>>(
        q_w, k_w, v_w, o_w, w1, w2, qkvT, oT, w1T, w2T);

    // ---- LN1 ----
    ln_bf16<<<BN, blk, 0, stream>>>(x, ln1g, ln1b, xn, D);

    // ---- fused QKV projection: [BN,3E], elu+1 on Q,K cols (768 blocks = 3.0 rounds) ----
    gemm2b<EPI_QKV, 256><<<dim3(E3 / 256, BN / 128), blk, 0, stream>>>(
        xn, qkvT, QKV, bcat, BN, E3, D, D, D, 0);

    // ---- V^T per batch: [N,E] (stride 3E) -> [E,N] ----
    transpose_u16<<<dim3(E / 32, N / 32, Bb), blk, 0, stream>>>(
        QKV + 2 * E, Vt, N, E, E3, (ll)N * E3, (ll)E * N);

    // ---- A = tril(Q K^T) per batch, fused rowsum -> den (BK=64) ----
    gemm_nt<EPI_TRIL, 64><<<dim3(N / 128, N / 128, Bb), blk, 0, stream>>>(
        QKV, QKV + E, Amat, nullptr, den, N, N, E, E3, E3,
        (ll)N * E3, (ll)N * E3, (ll)N * N, (ll)N);

    // ---- P = (A @ V) / den (triangular K-loop, BK=64) ----
    gemm_nt<EPI_DIV, 64><<<dim3(E / 128, N / 128, Bb), blk, 0, stream>>>(
        Amat, Vt, P, nullptr, den, N, E, N, N, N,
        (ll)N * N, (ll)E * N, (ll)N * E, (ll)N);

    // ---- split-K=2: parts = P @ o_w (fp32) -- gemm2b TNt=128, 512 blocks co-resident ----
    gemm2b<EPI_PART, 128><<<dim3(D / 128, BN / 128, 2), blk, 0, stream>>>(
        P, oT, pt0, nullptr, BN, D, E / 2, E, E, (ll)BN * D);

    // ---- x2 = x + p0 + p1 + o_b ; xn2 = LN2(x2) ----
    combine_ln<<<BN, blk, 0, stream>>>(x, pt0, pt1, o_b, ln2g, ln2b, x2, xn2);

    // ---- h = gelu(xn2 @ w1 + b1) (512 blocks = 2.0 rounds) ----
    gemm2b<EPI_GELU, 256><<<dim3(F / 256, BN / 128), blk, 0, stream>>>(
        xn2, w1T, h, b1, BN, F, D, D, D, 0);

    // ---- split-K=2: parts = h @ w2 (fp32) -- gemm2b TNt=128 ----
    gemm2b<EPI_PART, 128><<<dim3(D / 128, BN / 128, 2), blk, 0, stream>>>(
        h, w2T, pt0, nullptr, BN, D, F / 2, F, F, (ll)BN * D);

    // ---- out = x2 + p0 + p1 + b2 ----
    combine_out<<<dim3(BN * D / 4 / 256), blk, 0, stream>>>(x2, pt0, pt1, b2, out);
}

// Round 10
// 442.270 us; speedup vs baseline: 1.0319x; 1.0319x over previous
//
#include <hip/hip_runtime.h>
#include <math.h>

typedef unsigned short u16;
typedef short s16x8 __attribute__((ext_vector_type(8)));
typedef float f32x4 __attribute__((ext_vector_type(4)));
typedef long long ll;

__device__ inline u16 f2bf(float f) {
    unsigned u = __float_as_uint(f);
    u += 0x7fffu + ((u >> 16) & 1u);
    return (u16)(u >> 16);
}
__device__ inline float bf2f(u16 h) { return __uint_as_float(((unsigned)h) << 16); }

// async global->LDS, 16B per lane; LDS dest = wave-uniform base + lane*16
__device__ __forceinline__ void glds16(const u16* g, u16* l) {
    __builtin_amdgcn_global_load_lds(
        (__attribute__((address_space(1))) void*)(void*)g,
        (__attribute__((address_space(3))) void*)l, 16, 0, 0);
}

// ---------------- LayerNorm -> bf16 (one block per row, D=1024) ----------------
__global__ __launch_bounds__(256) void ln_bf16(const float* __restrict__ x,
                                               const float* __restrict__ g,
                                               const float* __restrict__ b,
                                               u16* __restrict__ out, int D) {
    int row = blockIdx.x;
    const float* xr = x + (size_t)row * D;
    int t = threadIdx.x;
    float4 v = ((const float4*)xr)[t];
    float s = v.x + v.y + v.z + v.w;
    __shared__ float sm[4];
    #pragma unroll
    for (int o = 32; o > 0; o >>= 1) s += __shfl_down(s, o, 64);
    int lane = t & 63, wv = t >> 6;
    if (lane == 0) sm[wv] = s;
    __syncthreads();
    float mean = (sm[0] + sm[1] + sm[2] + sm[3]) * (1.0f / 1024.0f);
    float dx = v.x - mean, dy = v.y - mean, dz = v.z - mean, dw = v.w - mean;
    float s2 = dx * dx + dy * dy + dz * dz + dw * dw;
    __syncthreads();
    #pragma unroll
    for (int o = 32; o > 0; o >>= 1) s2 += __shfl_down(s2, o, 64);
    if (lane == 0) sm[wv] = s2;
    __syncthreads();
    float var = (sm[0] + sm[1] + sm[2] + sm[3]) * (1.0f / 1024.0f);
    float rstd = rsqrtf(var + 1e-5f);
    float4 gg = ((const float4*)g)[t], bb = ((const float4*)b)[t];
    ushort4 o4;
    o4.x = f2bf(dx * rstd * gg.x + bb.x);
    o4.y = f2bf(dy * rstd * gg.y + bb.y);
    o4.z = f2bf(dz * rstd * gg.z + bb.z);
    o4.w = f2bf(dw * rstd * gg.w + bb.w);
    ((ushort4*)(out + (size_t)row * D))[t] = o4;
}

// ---------------- combine split-K parts + residual + bias, then LayerNorm ----------------
__global__ __launch_bounds__(256) void combine_ln(
    const float* __restrict__ x, const float* __restrict__ p0,
    const float* __restrict__ p1, const float* __restrict__ ob,
    const float* __restrict__ g, const float* __restrict__ b,
    float* __restrict__ x2, u16* __restrict__ xn2) {
    int row = blockIdx.x;
    int t = threadIdx.x;
    size_t base = (size_t)row * 256;  // float4 units
    float4 v = ((const float4*)x)[base + t];
    float4 a0 = ((const float4*)p0)[base + t];
    float4 a1 = ((const float4*)p1)[base + t];
    float4 ob4 = ((const float4*)ob)[t];
    v.x += a0.x + a1.x + ob4.x;
    v.y += a0.y + a1.y + ob4.y;
    v.z += a0.z + a1.z + ob4.z;
    v.w += a0.w + a1.w + ob4.w;
    ((float4*)x2)[base + t] = v;
    float s = v.x + v.y + v.z + v.w;
    __shared__ float sm[4];
    #pragma unroll
    for (int o = 32; o > 0; o >>= 1) s += __shfl_down(s, o, 64);
    int lane = t & 63, wv = t >> 6;
    if (lane == 0) sm[wv] = s;
    __syncthreads();
    float mean = (sm[0] + sm[1] + sm[2] + sm[3]) * (1.0f / 1024.0f);
    float dx = v.x - mean, dy = v.y - mean, dz = v.z - mean, dw = v.w - mean;
    float s2 = dx * dx + dy * dy + dz * dz + dw * dw;
    __syncthreads();
    #pragma unroll
    for (int o = 32; o > 0; o >>= 1) s2 += __shfl_down(s2, o, 64);
    if (lane == 0) sm[wv] = s2;
    __syncthreads();
    float var = (sm[0] + sm[1] + sm[2] + sm[3]) * (1.0f / 1024.0f);
    float rstd = rsqrtf(var + 1e-5f);
    float4 gg = ((const float4*)g)[t], bb = ((const float4*)b)[t];
    ushort4 o4;
    o4.x = f2bf(dx * rstd * gg.x + bb.x);
    o4.y = f2bf(dy * rstd * gg.y + bb.y);
    o4.z = f2bf(dz * rstd * gg.z + bb.z);
    o4.w = f2bf(dw * rstd * gg.w + bb.w);
    ((ushort4*)(xn2 + (size_t)row * 1024))[t] = o4;
}

// out = x2 + p0 + p1 + b2
__global__ __launch_bounds__(256) void combine_out(
    const float* __restrict__ x2, const float* __restrict__ p0,
    const float* __restrict__ p1, const float* __restrict__ b2,
    float* __restrict__ out) {
    size_t i = (size_t)blockIdx.x * 256 + threadIdx.x;
    int col4 = (int)(i & 255);
    float4 v = ((const float4*)x2)[i];
    float4 a0 = ((const float4*)p0)[i];
    float4 a1 = ((const float4*)p1)[i];
    float4 bb = ((const float4*)b2)[col4];
    v.x += a0.x + a1.x + bb.x;
    v.y += a0.y + a1.y + bb.y;
    v.z += a0.z + a1.z + bb.z;
    v.w += a0.w + a1.w + bb.w;
    ((float4*)out)[i] = v;
}

// ---------------- prep: pack q_b,k_b,v_b -> bcat[3E]; zero den[BN] ----------------
__global__ void prep(const float* __restrict__ qb, const float* __restrict__ kb,
                     const float* __restrict__ vb, float* __restrict__ bcat,
                     float* __restrict__ den, int E, int BN) {
    int i = blockIdx.x * 256 + threadIdx.x;
    if (i < E) {
        bcat[i] = qb[i];
        bcat[E + i] = kb[i];
        bcat[2 * E + i] = vb[i];
    }
    if (i < BN) den[i] = 0.f;
}

// ---------------- all 6 weight transposes in one dispatch ----------------
__global__ __launch_bounds__(256) void transpose_all(
    const float* __restrict__ q_w, const float* __restrict__ k_w,
    const float* __restrict__ v_w, const float* __restrict__ o_w,
    const float* __restrict__ w1, const float* __restrict__ w2,
    u16* __restrict__ qkvT, u16* __restrict__ oT,
    u16* __restrict__ w1T, u16* __restrict__ w2T) {
    int z = blockIdx.y;
    const float* src;
    u16* dst;
    int R, C, tprLog;  // tiles-per-row = C/32, log2
    switch (z) {
        case 0: src = q_w; dst = qkvT;                           R = 1024; C = 2048; tprLog = 6; break;
        case 1: src = k_w; dst = qkvT + (size_t)2 * 1024 * 1024; R = 1024; C = 2048; tprLog = 6; break;
        case 2: src = v_w; dst = qkvT + (size_t)4 * 1024 * 1024; R = 1024; C = 2048; tprLog = 6; break;
        case 3: src = o_w; dst = oT;                             R = 2048; C = 1024; tprLog = 5; break;
        case 4: src = w1;  dst = w1T;                            R = 1024; C = 4096; tprLog = 7; break;
        default: src = w2; dst = w2T;                            R = 4096; C = 1024; tprLog = 5; break;
    }
    int bx = blockIdx.x;
    int ntiles = (R >> 5) << (tprLog);
    if (bx >= ntiles) return;
    int c0 = (bx & ((1 << tprLog) - 1)) * 32;
    int r0 = (bx >> tprLog) * 32;
    __shared__ u16 tile[32][33];
    int tx = threadIdx.x & 31, ty = threadIdx.x >> 5;
    #pragma unroll
    for (int i = 0; i < 32; i += 8)
        tile[ty + i][tx] = f2bf(src[(size_t)(r0 + ty + i) * C + c0 + tx]);
    __syncthreads();
    #pragma unroll
    for (int i = 0; i < 32; i += 8)
        dst[(size_t)(c0 + ty + i) * R + r0 + tx] = tile[tx][ty + i];
}

// generic bf16 transpose (used for V^T): in [R,C] (row stride ldIn) -> out [C,R]
__global__ __launch_bounds__(256) void transpose_u16(const u16* __restrict__ in,
                                                     u16* __restrict__ out,
                                                     int R, int C, int ldIn,
                                                     ll sIn, ll sOut) {
    in += (size_t)blockIdx.z * sIn;
    out += (size_t)blockIdx.z * sOut;
    __shared__ u16 tile[32][33];
    int tx = threadIdx.x & 31, ty = threadIdx.x >> 5;
    int c0 = blockIdx.x * 32, r0 = blockIdx.y * 32;
    #pragma unroll
    for (int i = 0; i < 32; i += 8)
        tile[ty + i][tx] = in[(size_t)(r0 + ty + i) * ldIn + c0 + tx];
    __syncthreads();
    #pragma unroll
    for (int i = 0; i < 32; i += 8)
        out[(size_t)(c0 + ty + i) * R + r0 + tx] = tile[tx][ty + i];
}

// ---------------- unified GEMM NT 128xTNt, 4-wave, BK=32, 3-buf counted-vmcnt ----------------
// ALL GEMMs now run this one template (gemm_nt deleted).
// TNt=256: wave tile 64x128, LDS 72KB -> 2 blocks/CU (QKV/GELU; R8-proven:
//   0 bank conflicts, coalesced, 70us QKV).
// TNt=128: wave tile 64x64, LDS 48KB -> 3 blocks/CU capacity (PART/TRIL/DIV).
// Layout: row-major + 16B-chunk XOR swizzle at row-pair granularity:
//   staging row = lane>>2 (coalesced 64B/quad), source chunk pre-swizzled
//   ((lane&3)-((lane>>3)&3))&3 so linear LDS dest stores chunk'=(c+(row>>1))&3;
//   frag read chunk' = (q+(lr>>1))&3 -> 2 lanes/bank-quad = free (m136).
// Schedule: 2-phase / 3-buffer; stage t+2 during t; end-of-tile counted vmcnt
//   (6 for TNt=256: 2A+4B loads/tile; 4 for TNt=128: 2A+2B) drains t+1 exactly;
//   no forced lgkmcnt (compiler fine-grains; MFMA overlaps LDS drain).
// Block->tile mapping: TRIL/DIV panel-of-4 (keeps kend load spread / diag
//   blocks mixed across XCDs); others per-XCD rectangle.
// Per-z strides sA,sB (elements), sC (elements of C's type), sAux (den rows).
// EPI_PART: split-K via z (sA=sB=K advance within rows; fp32 C += z*sC).
// EPI_TRIL: zero-fill early-out above diagonal; epilogue mask + rowsum atomics.
// EPI_DIV: triangular kend=min(m0+128,K) (nk>=4 -> 3-buf prologue safe);
//   epilogue divides by den.
// Grid MUST be (N/TNt, M/128[, z]) with gridDim.x%4==0, gridDim.y%2==0.
enum { EPI_QKV = 0, EPI_TRIL = 2, EPI_DIV = 3, EPI_GELU = 5, EPI_PART = 6 };

template <int EPI, int TNt>
__global__ __launch_bounds__(256, 2) void gemm2b(
    const u16* __restrict__ A, const u16* __restrict__ B, void* __restrict__ Cv,
    const float* __restrict__ bias, float* __restrict__ den,
    int M, int N, int K, int lda, int ldb,
    ll sA, ll sB, ll sC, ll sAux) {

    constexpr int NJ = TNt / 32;          // B frags per wave (8 or 4)
    constexpr int BUF = 4096 + TNt * 32;  // u16 per buffer
    __shared__ __align__(16) u16 lds[3][BUF];

    int z = blockIdx.z;
    A += (size_t)z * sA;
    B += (size_t)z * sB;

    int p = blockIdx.y * gridDim.x + blockIdx.x;
    int m0, n0;
    if (EPI == EPI_TRIL || EPI == EPI_DIV) {
        // panel-of-4 swizzle (proven; spreads long/short-kend blocks)
        int nb = gridDim.x;
        int panel = nb * 4;
        int pp = p / panel, rr2 = p - pp * panel;
        m0 = (pp * 4 + (rr2 & 3)) * 128;
        n0 = (rr2 >> 2) * TNt;
    } else {
        int g = p & 7, rr2 = p >> 3;
        int lw = gridDim.x >> 2, lh = gridDim.y >> 1;
        int ly = rr2 / lw, lx = rr2 - ly * lw;
        m0 = ((g >> 2) * lh + ly) * 128;
        n0 = ((g & 3) * lw + lx) * TNt;
    }

    int t = threadIdx.x;

    // strictly-above-diagonal tril blocks: write zeros, done (block-uniform)
    if (EPI == EPI_TRIL && n0 > m0 + 127) {
        u16* C = (u16*)Cv + (size_t)z * sC;
        #pragma unroll
        for (int s = 0; s < 8; ++s) {
            int v = t + 256 * s;
            int row = v >> 4, cf = (v & 15) * 8;
            *(uint4*)&C[(size_t)(m0 + row) * N + n0 + cf] = make_uint4(0, 0, 0, 0);
        }
        return;
    }

    int lane = t & 63, wid = t >> 6;  // 4 waves
    int lr = lane & 15, q = lane >> 4;

    // staging: row = lane>>2 (coalesced 64B per quad-lane), pre-swizzled chunk
    int skf = (((lane & 3) - ((lane >> 3) & 3)) & 3) * 8;
    const u16* gA = A + (size_t)(m0 + wid * 32 + (lane >> 2)) * lda + skf;
    const u16* gB = B + (size_t)(n0 + wid * (TNt / 4) + (lane >> 2)) * ldb + skf;
    int sdA = wid * 1024;                  // wave's 32 A-rows
    int sdB = 4096 + wid * (TNt * 32 / 4); // wave's TNt/4 B-rows

    int kend = (EPI == EPI_DIV) ? (m0 + 128 < K ? m0 + 128 : K) : K;
    int nk = kend >> 5;

    auto stageA = [&](int tt, int d) {
        int kt = (tt < nk ? tt : nk - 1) << 5;
        glds16(gA + kt, &lds[d][sdA]);
        glds16(gA + kt + (size_t)16 * lda, &lds[d][sdA + 512]);
    };
    auto stageB = [&](int tt, int d) {
        int kt = (tt < nk ? tt : nk - 1) << 5;
        #pragma unroll
        for (int r2 = 0; r2 < TNt / 64; ++r2)
            glds16(gB + kt + (size_t)(16 * r2) * ldb, &lds[d][sdB + r2 * 512]);
    };

    f32x4 acc[4][NJ];
    #pragma unroll
    for (int i = 0; i < 4; i++)
        #pragma unroll
        for (int j = 0; j < NJ; j++) { f32x4 zz = {0.f, 0.f, 0.f, 0.f}; acc[i][j] = zz; }

    int wm = (wid & 1) * 64, wn = (wid >> 1) * (TNt / 2);
    // swizzled frag offsets (u16): row*32 + ((q + (lr>>1))&3)*8; frag i/j adds 512
    int csw = ((q + (lr >> 1)) & 3) * 8;
    int aoff = (wm + lr) * 32 + csw;
    int boff = 4096 + (wn + lr) * 32 + csw;

    // ---- prologue: tiles 0,1 staged ----
    stageA(0, 0); stageB(0, 0);
    stageA(1, 1); stageB(1, 1);
    if constexpr (TNt == 256) asm volatile("s_waitcnt vmcnt(6)" ::: "memory");
    else                      asm volatile("s_waitcnt vmcnt(4)" ::: "memory");
    asm volatile("s_barrier" ::: "memory");

    s16x8 af[4], bf_[NJ];

    int cur = 0;
    for (int tt = 0; tt < nk; ++tt) {
        int nx2 = cur + 2; if (nx2 >= 3) nx2 -= 3;
        const u16* L = &lds[cur][0];

        // ---- phase 1: ds B(j<NJ/2) + A(all) | stage B(t+2) | mfma j<NJ/2 ----
        #pragma unroll
        for (int j = 0; j < NJ / 2; j++) bf_[j] = *(const s16x8*)&L[boff + j * 512];
        #pragma unroll
        for (int i = 0; i < 4; i++) af[i] = *(const s16x8*)&L[aoff + i * 512];
        stageB(tt + 2, nx2);
        asm volatile("s_barrier" ::: "memory");
        __builtin_amdgcn_s_setprio(1);
        #pragma unroll
        for (int i = 0; i < 4; i++)
            #pragma unroll
            for (int j = 0; j < NJ / 2; j++)
                acc[i][j] = __builtin_amdgcn_mfma_f32_16x16x32_bf16(af[i], bf_[j], acc[i][j], 0, 0, 0);
        __builtin_amdgcn_s_setprio(0);
        asm volatile("s_barrier" ::: "memory");

        // ---- phase 2: ds B(j>=NJ/2) | stage A(t+2) | mfma j>=NJ/2 | vmcnt ----
        #pragma unroll
        for (int j = NJ / 2; j < NJ; j++) bf_[j] = *(const s16x8*)&L[boff + j * 512];
        stageA(tt + 2, nx2);
        asm volatile("s_barrier" ::: "memory");
        __builtin_amdgcn_s_setprio(1);
        #pragma unroll
        for (int i = 0; i < 4; i++)
            #pragma unroll
            for (int j = NJ / 2; j < NJ; j++)
                acc[i][j] = __builtin_amdgcn_mfma_f32_16x16x32_bf16(af[i], bf_[j], acc[i][j], 0, 0, 0);
        __builtin_amdgcn_s_setprio(0);
        if constexpr (TNt == 256) asm volatile("s_waitcnt vmcnt(6)" ::: "memory");  // t+1 landed; never 0
        else                      asm volatile("s_waitcnt vmcnt(4)" ::: "memory");
        asm volatile("s_barrier" ::: "memory");

        cur = cur + 1; if (cur >= 3) cur -= 3;
    }

    asm volatile("s_waitcnt vmcnt(0)" ::: "memory");  // drain DMA before LDS dealloc

    // ---- epilogue ----
    u16* Cb = (u16*)Cv + (size_t)z * ((EPI == EPI_PART) ? 0 : sC);
    float* Cf = (float*)Cv + (size_t)z * ((EPI == EPI_PART) ? sC : 0);
    bool isQKcol = (EPI == EPI_QKV);
    #pragma unroll
    for (int i = 0; i < 4; i++) {
        #pragma unroll
        for (int r = 0; r < 4; r++) {
            int row = m0 + wm + i * 16 + q * 4 + r;
            float rs = 0.f;
            #pragma unroll
            for (int j = 0; j < NJ; j++) {
                int col = n0 + wn + j * 16 + lr;
                float v = acc[i][j][r];
                if (EPI == EPI_PART) {
                    Cf[(size_t)row * N + col] = v;
                } else if (EPI == EPI_TRIL) {
                    v = (col <= row) ? v : 0.f;
                    rs += v;
                    Cb[(size_t)row * N + col] = f2bf(v);
                } else if (EPI == EPI_DIV) {
                    float d = den[(size_t)z * sAux + row] + 1e-6f;
                    Cb[(size_t)row * N + col] = f2bf(v / d);
                } else {
                    v += bias[col];
                    if (EPI == EPI_QKV) {
                        if (isQKcol && (n0 + wn + j * 16 < 4096)) v = (v > 0.f) ? (v + 1.f) : __expf(v);  // elu+1
                    } else {  // EPI_GELU
                        float u = v * (0.7978845608f + 0.0356774081f * v * v);
                        u = fminf(u, 40.f);
                        float e = __expf(2.f * u);
                        v = v * __fdividef(e, e + 1.f);
                    }
                    Cb[(size_t)row * N + col] = f2bf(v);
                }
            }
            if (EPI == EPI_TRIL) {
                #pragma unroll
                for (int m = 1; m < 16; m <<= 1) rs += __shfl_xor(rs, m, 16);
                if (lr == 0) atomicAdd(&den[(size_t)z * sAux + row], rs);
            }
        }
    }
}

extern "C" void kernel_launch(void* const* d_in, const int* in_sizes, int n_in,
                              void* d_out, int out_size, void* d_ws, size_t ws_size,
                              hipStream_t stream) {
    const float* x    = (const float*)d_in[0];
    const float* q_w  = (const float*)d_in[1];
    const float* q_b  = (const float*)d_in[2];
    const float* k_w  = (const float*)d_in[3];
    const float* k_b  = (const float*)d_in[4];
    const float* v_w  = (const float*)d_in[5];
    const float* v_b  = (const float*)d_in[6];
    const float* o_w  = (const float*)d_in[7];
    const float* o_b  = (const float*)d_in[8];
    const float* ln1g = (const float*)d_in[9];
    const float* ln1b = (const float*)d_in[10];
    const float* ln2g = (const float*)d_in[11];
    const float* ln2b = (const float*)d_in[12];
    const float* w1   = (const float*)d_in[13];
    const float* b1   = (const float*)d_in[14];
    const float* w2   = (const float*)d_in[15];
    const float* b2   = (const float*)d_in[16];
    float* out = (float*)d_out;

    constexpr int Bb = 2, N = 2048, D = 1024, E = 2048, F = 4096;
    constexpr int BN = Bb * N;     // 4096
    constexpr int E3 = 3 * E;      // 6144

    char* ws = (char*)d_ws;
    size_t off = 0;
    auto alloc = [&](size_t bytes) -> void* {
        void* p = ws + off;
        off += (bytes + 255) & ~(size_t)255;
        return p;
    };
    u16*   qkvT = (u16*)alloc((size_t)E3 * D * 2);     // 12 MB
    u16*   oT   = (u16*)alloc((size_t)D * E * 2);      // 4 MB
    u16*   w1T  = (u16*)alloc((size_t)F * D * 2);      // 8 MB
    u16*   w2T  = (u16*)alloc((size_t)D * F * 2);      // 8 MB
    float* bcat = (float*)alloc((size_t)E3 * 4);
    u16*   xn   = (u16*)alloc((size_t)BN * D * 2);     // 8 MB (reused as xn2)
    u16*   QKV  = (u16*)alloc((size_t)BN * E3 * 2);    // 48 MB (reused: P, h)
    u16*   Vt   = (u16*)alloc((size_t)Bb * E * N * 2); // 16 MB (reused as x2 fp32)
    u16*   Amat = (u16*)alloc((size_t)Bb * N * N * 2); // 32 MB (reused as parts)
    float* den  = (float*)alloc((size_t)BN * 4);

    u16*   xn2 = xn;
    u16*   P   = QKV;                  // [BN,E] bf16
    u16*   h   = QKV + (size_t)8 * 1024 * 1024;  // [BN,F] bf16
    float* x2  = (float*)Vt;           // [BN,D] fp32
    float* pt0 = (float*)Amat;         // split-K partial 0
    float* pt1 = pt0 + (size_t)BN * D; // split-K partial 1

    dim3 blk(256);

    // ---- prep: biases + den zero ----
    prep<<<dim3((BN + 255) / 256), blk, 0, stream>>>(q_b, k_b, v_b, bcat, den, E, BN);

    // ---- all weight transposes, one dispatch ----
    transpose_all<<<dim3(4096, 6), blk, 0, stream>>>(
        q_w, k_w, v_w, o_w, w1, w2, qkvT, oT, w1T, w2T);

    // ---- LN1 ----
    ln_bf16<<<BN, blk, 0, stream>>>(x, ln1g, ln1b, xn, D);

    // ---- fused QKV projection: [BN,3E], elu+1 on Q,K cols (768 blocks = 3.0 rounds) ----
    gemm2b<EPI_QKV, 256><<<dim3(E3 / 256, BN / 128), blk, 0, stream>>>(
        xn, qkvT, QKV, bcat, nullptr, BN, E3, D, D, D, 0, 0, 0, 0);

    // ---- V^T per batch: [N,E] (stride 3E) -> [E,N] ----
    transpose_u16<<<dim3(E / 32, N / 32, Bb), blk, 0, stream>>>(
        QKV + 2 * E, Vt, N, E, E3, (ll)N * E3, (ll)E * N);

    // ---- A = tril(Q K^T) per batch, fused rowsum -> den (gemm2b TNt=128) ----
    gemm2b<EPI_TRIL, 128><<<dim3(N / 128, N / 128, Bb), blk, 0, stream>>>(
        QKV, QKV + E, Amat, nullptr, den, N, N, E, E3, E3,
        (ll)N * E3, (ll)N * E3, (ll)N * N, (ll)N);

    // ---- P = (A @ V) / den (triangular kend, gemm2b TNt=128) ----
    gemm2b<EPI_DIV, 128><<<dim3(E / 128, N / 128, Bb), blk, 0, stream>>>(
        Amat, Vt, P, nullptr, den, N, E, N, N, N,
        (ll)N * N, (ll)E * N, (ll)N * E, (ll)N);

    // ---- split-K=2: parts = P @ o_w (fp32) -- gemm2b TNt=128 ----
    gemm2b<EPI_PART, 128><<<dim3(D / 128, BN / 128, 2), blk, 0, stream>>>(
        P, oT, pt0, nullptr, nullptr, BN, D, E / 2, E, E,
        (ll)(E / 2), (ll)(E / 2), (ll)BN * D, 0);

    // ---- x2 = x + p0 + p1 + o_b ; xn2 = LN2(x2) ----
    combine_ln<<<BN, blk, 0, stream>>>(x, pt0, pt1, o_b, ln2g, ln2b, x2, xn2);

    // ---- h = gelu(xn2 @ w1 + b1) (512 blocks = 2.0 rounds) ----
    gemm2b<EPI_GELU, 256><<<dim3(F / 256, BN / 128), blk, 0, stream>>>(
        xn2, w1T, h, b1, nullptr, BN, F, D, D, D, 0, 0, 0, 0);

    // ---- split-K=2: parts = h @ w2 (fp32) -- gemm2b TNt=128 ----
    gemm2b<EPI_PART, 128><<<dim3(D / 128, BN / 128, 2), blk, 0, stream>>>(
        h, w2T, pt0, nullptr, nullptr, BN, D, F / 2, F, F,
        (ll)(F / 2), (ll)(F / 2), (ll)BN * D, 0);

    // ---- out = x2 + p0 + p1 + b2 ----
    combine_out<<<dim3(BN * D / 4 / 256), blk, 0, stream>>>(x2, pt0, pt1, b2, out);
}

// Round 11
// 427.005 us; speedup vs baseline: 1.0688x; 1.0358x over previous
//
#include <hip/hip_runtime.h>
#include <math.h>

typedef unsigned short u16;
typedef short s16x8 __attribute__((ext_vector_type(8)));
typedef float f32x4 __attribute__((ext_vector_type(4)));
typedef long long ll;

__device__ inline u16 f2bf(float f) {
    unsigned u = __float_as_uint(f);
    u += 0x7fffu + ((u >> 16) & 1u);
    return (u16)(u >> 16);
}

// async global->LDS, 16B per lane; LDS dest = wave-uniform base + lane*16
__device__ __forceinline__ void glds16(const u16* g, u16* l) {
    __builtin_amdgcn_global_load_lds(
        (__attribute__((address_space(1))) void*)(void*)g,
        (__attribute__((address_space(3))) void*)l, 16, 0, 0);
}

// ---------------- preproc: 6 weight transposes + LN1 + bias-pack + den-zero ----------------
// grid (4096, 7): y=0..5 -> fp32->bf16 transposes; y=6 -> LN1 row per block
// (+ first 24 blocks pack q_b/k_b/v_b into bcat, first 16 zero den).
__global__ __launch_bounds__(256) void preproc(
    const float* __restrict__ q_w, const float* __restrict__ k_w,
    const float* __restrict__ v_w, const float* __restrict__ o_w,
    const float* __restrict__ w1, const float* __restrict__ w2,
    u16* __restrict__ qkvT, u16* __restrict__ oT,
    u16* __restrict__ w1T, u16* __restrict__ w2T,
    const float* __restrict__ x, const float* __restrict__ g,
    const float* __restrict__ b, u16* __restrict__ xn,
    const float* __restrict__ qb, const float* __restrict__ kb,
    const float* __restrict__ vb, float* __restrict__ bcat,
    float* __restrict__ den) {
    __shared__ u16 tile[32][33];
    __shared__ float sm[4];
    int z = blockIdx.y;
    int t = threadIdx.x;

    if (z == 6) {
        int row = blockIdx.x;
        int i = row * 256 + t;
        if (i < 2048) { bcat[i] = qb[i]; bcat[2048 + i] = kb[i]; bcat[4096 + i] = vb[i]; }
        if (i < 4096) den[i] = 0.f;
        // LayerNorm row -> bf16 (D=1024)
        const float* xr = x + (size_t)row * 1024;
        float4 v = ((const float4*)xr)[t];
        float s = v.x + v.y + v.z + v.w;
        #pragma unroll
        for (int o = 32; o > 0; o >>= 1) s += __shfl_down(s, o, 64);
        int lane = t & 63, wv = t >> 6;
        if (lane == 0) sm[wv] = s;
        __syncthreads();
        float mean = (sm[0] + sm[1] + sm[2] + sm[3]) * (1.0f / 1024.0f);
        float dx = v.x - mean, dy = v.y - mean, dz = v.z - mean, dw = v.w - mean;
        float s2 = dx * dx + dy * dy + dz * dz + dw * dw;
        __syncthreads();
        #pragma unroll
        for (int o = 32; o > 0; o >>= 1) s2 += __shfl_down(s2, o, 64);
        if (lane == 0) sm[wv] = s2;
        __syncthreads();
        float var = (sm[0] + sm[1] + sm[2] + sm[3]) * (1.0f / 1024.0f);
        float rstd = rsqrtf(var + 1e-5f);
        float4 gg = ((const float4*)g)[t], bb = ((const float4*)b)[t];
        ushort4 o4;
        o4.x = f2bf(dx * rstd * gg.x + bb.x);
        o4.y = f2bf(dy * rstd * gg.y + bb.y);
        o4.z = f2bf(dz * rstd * gg.z + bb.z);
        o4.w = f2bf(dw * rstd * gg.w + bb.w);
        ((ushort4*)(xn + (size_t)row * 1024))[t] = o4;
        return;
    }

    const float* src;
    u16* dst;
    int R, C, tprLog;  // tiles-per-row = C/32, log2
    switch (z) {
        case 0: src = q_w; dst = qkvT;                           R = 1024; C = 2048; tprLog = 6; break;
        case 1: src = k_w; dst = qkvT + (size_t)2 * 1024 * 1024; R = 1024; C = 2048; tprLog = 6; break;
        case 2: src = v_w; dst = qkvT + (size_t)4 * 1024 * 1024; R = 1024; C = 2048; tprLog = 6; break;
        case 3: src = o_w; dst = oT;                             R = 2048; C = 1024; tprLog = 5; break;
        case 4: src = w1;  dst = w1T;                            R = 1024; C = 4096; tprLog = 7; break;
        default: src = w2; dst = w2T;                            R = 4096; C = 1024; tprLog = 5; break;
    }
    int bx = blockIdx.x;
    int ntiles = (R >> 5) << (tprLog);
    if (bx >= ntiles) return;
    int c0 = (bx & ((1 << tprLog) - 1)) * 32;
    int r0 = (bx >> tprLog) * 32;
    int tx = t & 31, ty = t >> 5;
    #pragma unroll
    for (int i = 0; i < 32; i += 8)
        tile[ty + i][tx] = f2bf(src[(size_t)(r0 + ty + i) * C + c0 + tx]);
    __syncthreads();
    #pragma unroll
    for (int i = 0; i < 32; i += 8)
        dst[(size_t)(c0 + ty + i) * R + r0 + tx] = tile[tx][ty + i];
}

// ---------------- combine split-K parts + residual + bias, then LayerNorm ----------------
__global__ __launch_bounds__(256) void combine_ln(
    const float* __restrict__ x, const float* __restrict__ p0,
    const float* __restrict__ p1, const float* __restrict__ ob,
    const float* __restrict__ g, const float* __restrict__ b,
    float* __restrict__ x2, u16* __restrict__ xn2) {
    int row = blockIdx.x;
    int t = threadIdx.x;
    size_t base = (size_t)row * 256;  // float4 units
    float4 v = ((const float4*)x)[base + t];
    float4 a0 = ((const float4*)p0)[base + t];
    float4 a1 = ((const float4*)p1)[base + t];
    float4 ob4 = ((const float4*)ob)[t];
    v.x += a0.x + a1.x + ob4.x;
    v.y += a0.y + a1.y + ob4.y;
    v.z += a0.z + a1.z + ob4.z;
    v.w += a0.w + a1.w + ob4.w;
    ((float4*)x2)[base + t] = v;
    float s = v.x + v.y + v.z + v.w;
    __shared__ float sm[4];
    #pragma unroll
    for (int o = 32; o > 0; o >>= 1) s += __shfl_down(s, o, 64);
    int lane = t & 63, wv = t >> 6;
    if (lane == 0) sm[wv] = s;
    __syncthreads();
    float mean = (sm[0] + sm[1] + sm[2] + sm[3]) * (1.0f / 1024.0f);
    float dx = v.x - mean, dy = v.y - mean, dz = v.z - mean, dw = v.w - mean;
    float s2 = dx * dx + dy * dy + dz * dz + dw * dw;
    __syncthreads();
    #pragma unroll
    for (int o = 32; o > 0; o >>= 1) s2 += __shfl_down(s2, o, 64);
    if (lane == 0) sm[wv] = s2;
    __syncthreads();
    float var = (sm[0] + sm[1] + sm[2] + sm[3]) * (1.0f / 1024.0f);
    float rstd = rsqrtf(var + 1e-5f);
    float4 gg = ((const float4*)g)[t], bb = ((const float4*)b)[t];
    ushort4 o4;
    o4.x = f2bf(dx * rstd * gg.x + bb.x);
    o4.y = f2bf(dy * rstd * gg.y + bb.y);
    o4.z = f2bf(dz * rstd * gg.z + bb.z);
    o4.w = f2bf(dw * rstd * gg.w + bb.w);
    ((ushort4*)(xn2 + (size_t)row * 1024))[t] = o4;
}

// out = x2 + p0 + p1 + b2
__global__ __launch_bounds__(256) void combine_out(
    const float* __restrict__ x2, const float* __restrict__ p0,
    const float* __restrict__ p1, const float* __restrict__ b2,
    float* __restrict__ out) {
    size_t i = (size_t)blockIdx.x * 256 + threadIdx.x;
    int col4 = (int)(i & 255);
    float4 v = ((const float4*)x2)[i];
    float4 a0 = ((const float4*)p0)[i];
    float4 a1 = ((const float4*)p1)[i];
    float4 bb = ((const float4*)b2)[col4];
    v.x += a0.x + a1.x + bb.x;
    v.y += a0.y + a1.y + bb.y;
    v.z += a0.z + a1.z + bb.z;
    v.w += a0.w + a1.w + bb.w;
    ((float4*)out)[i] = v;
}

// ---------------- unified GEMM NT 128xTNt, 4-wave, BK=32, 3-buf counted-vmcnt ----------------
// TNt=256: wave tile 64x128, LDS 72KB -> 2 blocks/CU (QKV/GELU; R8-proven:
//   0 bank conflicts, coalesced, 70us QKV).
// TNt=128: wave tile 64x64, LDS 48KB -> 3 blocks/CU capacity (PART/TRIL/DIV).
// Layout: row-major + 16B-chunk XOR swizzle at row-pair granularity:
//   staging row = lane>>2 (coalesced 64B/quad), source chunk pre-swizzled
//   ((lane&3)-((lane>>3)&3))&3 so linear LDS dest stores chunk'=(c+(row>>1))&3;
//   frag read chunk' = (q+(lr>>1))&3 -> 2 lanes/bank-quad = free (m136).
// Schedule: 2-phase / 3-buffer; stage t+2 during t; end-of-tile counted vmcnt
//   (6 for TNt=256: 2A+4B loads/tile; 4 for TNt=128: 2A+2B) drains t+1 exactly.
// EPI_QKV + n0>=4096 (V columns): epilogue LDS-bounce transpose writes Vt
//   (aux) DIRECTLY -- eliminates the separate V^T kernel + 32MB roundtrip.
//   LDS free after loop (vmcnt(0) + __syncthreads); pad-136 layout: writes
//   2-way banked, reads contiguous, global stores 256B-coalesced segments.
// EPI_PART: split-K via z (sA=sB advance within rows; fp32 C += z*sC).
// EPI_TRIL: zero-fill early-out above diagonal; epilogue mask+rowsum atomics.
// EPI_DIV: triangular kend=min(m0+128,K); epilogue divides by den.
// Grid MUST be (N/TNt, M/128[, z]) with gridDim.x%4==0, gridDim.y%2==0.
enum { EPI_QKV = 0, EPI_TRIL = 2, EPI_DIV = 3, EPI_GELU = 5, EPI_PART = 6 };

template <int EPI, int TNt>
__global__ __launch_bounds__(256, 2) void gemm2b(
    const u16* __restrict__ A, const u16* __restrict__ B, void* __restrict__ Cv,
    const float* __restrict__ bias, float* __restrict__ den, u16* __restrict__ aux,
    int M, int N, int K, int lda, int ldb,
    ll sA, ll sB, ll sC, ll sAux) {

    constexpr int NJ = TNt / 32;          // B frags per wave (8 or 4)
    constexpr int BUF = 4096 + TNt * 32;  // u16 per buffer
    __shared__ __align__(16) u16 lds[3][BUF];

    int z = blockIdx.z;
    A += (size_t)z * sA;
    B += (size_t)z * sB;

    int p = blockIdx.y * gridDim.x + blockIdx.x;
    int m0, n0;
    if (EPI == EPI_TRIL || EPI == EPI_DIV) {
        // panel-of-4 swizzle (proven; spreads long/short-kend blocks)
        int nb = gridDim.x;
        int panel = nb * 4;
        int pp = p / panel, rr2 = p - pp * panel;
        m0 = (pp * 4 + (rr2 & 3)) * 128;
        n0 = (rr2 >> 2) * TNt;
    } else {
        int g = p & 7, rr2 = p >> 3;
        int lw = gridDim.x >> 2, lh = gridDim.y >> 1;
        int ly = rr2 / lw, lx = rr2 - ly * lw;
        m0 = ((g >> 2) * lh + ly) * 128;
        n0 = ((g & 3) * lw + lx) * TNt;
    }

    int t = threadIdx.x;

    // strictly-above-diagonal tril blocks: write zeros, done (block-uniform)
    if (EPI == EPI_TRIL && n0 > m0 + 127) {
        u16* C = (u16*)Cv + (size_t)z * sC;
        #pragma unroll
        for (int s = 0; s < 8; ++s) {
            int v = t + 256 * s;
            int row = v >> 4, cf = (v & 15) * 8;
            *(uint4*)&C[(size_t)(m0 + row) * N + n0 + cf] = make_uint4(0, 0, 0, 0);
        }
        return;
    }

    int lane = t & 63, wid = t >> 6;  // 4 waves
    int lr = lane & 15, q = lane >> 4;

    // staging: row = lane>>2 (coalesced 64B per quad-lane), pre-swizzled chunk
    int skf = (((lane & 3) - ((lane >> 3) & 3)) & 3) * 8;
    const u16* gA = A + (size_t)(m0 + wid * 32 + (lane >> 2)) * lda + skf;
    const u16* gB = B + (size_t)(n0 + wid * (TNt / 4) + (lane >> 2)) * ldb + skf;
    int sdA = wid * 1024;                  // wave's 32 A-rows
    int sdB = 4096 + wid * (TNt * 32 / 4); // wave's TNt/4 B-rows

    int kend = (EPI == EPI_DIV) ? (m0 + 128 < K ? m0 + 128 : K) : K;
    int nk = kend >> 5;

    auto stageA = [&](int tt, int d) {
        int kt = (tt < nk ? tt : nk - 1) << 5;
        glds16(gA + kt, &lds[d][sdA]);
        glds16(gA + kt + (size_t)16 * lda, &lds[d][sdA + 512]);
    };
    auto stageB = [&](int tt, int d) {
        int kt = (tt < nk ? tt : nk - 1) << 5;
        #pragma unroll
        for (int r2 = 0; r2 < TNt / 64; ++r2)
            glds16(gB + kt + (size_t)(16 * r2) * ldb, &lds[d][sdB + r2 * 512]);
    };

    f32x4 acc[4][NJ];
    #pragma unroll
    for (int i = 0; i < 4; i++)
        #pragma unroll
        for (int j = 0; j < NJ; j++) { f32x4 zz = {0.f, 0.f, 0.f, 0.f}; acc[i][j] = zz; }

    int wm = (wid & 1) * 64, wn = (wid >> 1) * (TNt / 2);
    // swizzled frag offsets (u16): row*32 + ((q + (lr>>1))&3)*8; frag i/j adds 512
    int csw = ((q + (lr >> 1)) & 3) * 8;
    int aoff = (wm + lr) * 32 + csw;
    int boff = 4096 + (wn + lr) * 32 + csw;

    // ---- prologue: tiles 0,1 staged ----
    stageA(0, 0); stageB(0, 0);
    stageA(1, 1); stageB(1, 1);
    if constexpr (TNt == 256) asm volatile("s_waitcnt vmcnt(6)" ::: "memory");
    else                      asm volatile("s_waitcnt vmcnt(4)" ::: "memory");
    asm volatile("s_barrier" ::: "memory");

    s16x8 af[4], bf_[NJ];

    int cur = 0;
    for (int tt = 0; tt < nk; ++tt) {
        int nx2 = cur + 2; if (nx2 >= 3) nx2 -= 3;
        const u16* L = &lds[cur][0];

        // ---- phase 1: ds B(j<NJ/2) + A(all) | stage B(t+2) | mfma j<NJ/2 ----
        #pragma unroll
        for (int j = 0; j < NJ / 2; j++) bf_[j] = *(const s16x8*)&L[boff + j * 512];
        #pragma unroll
        for (int i = 0; i < 4; i++) af[i] = *(const s16x8*)&L[aoff + i * 512];
        stageB(tt + 2, nx2);
        asm volatile("s_barrier" ::: "memory");
        __builtin_amdgcn_s_setprio(1);
        #pragma unroll
        for (int i = 0; i < 4; i++)
            #pragma unroll
            for (int j = 0; j < NJ / 2; j++)
                acc[i][j] = __builtin_amdgcn_mfma_f32_16x16x32_bf16(af[i], bf_[j], acc[i][j], 0, 0, 0);
        __builtin_amdgcn_s_setprio(0);
        asm volatile("s_barrier" ::: "memory");

        // ---- phase 2: ds B(j>=NJ/2) | stage A(t+2) | mfma j>=NJ/2 | vmcnt ----
        #pragma unroll
        for (int j = NJ / 2; j < NJ; j++) bf_[j] = *(const s16x8*)&L[boff + j * 512];
        stageA(tt + 2, nx2);
        asm volatile("s_barrier" ::: "memory");
        __builtin_amdgcn_s_setprio(1);
        #pragma unroll
        for (int i = 0; i < 4; i++)
            #pragma unroll
            for (int j = NJ / 2; j < NJ; j++)
                acc[i][j] = __builtin_amdgcn_mfma_f32_16x16x32_bf16(af[i], bf_[j], acc[i][j], 0, 0, 0);
        __builtin_amdgcn_s_setprio(0);
        if constexpr (TNt == 256) asm volatile("s_waitcnt vmcnt(6)" ::: "memory");  // t+1 landed; never 0
        else                      asm volatile("s_waitcnt vmcnt(4)" ::: "memory");
        asm volatile("s_barrier" ::: "memory");

        cur = cur + 1; if (cur >= 3) cur -= 3;
    }

    asm volatile("s_waitcnt vmcnt(0)" ::: "memory");  // drain own DMA

    // ---- V-column QKV blocks: LDS-bounce transpose -> Vt directly ----
    if constexpr (EPI == EPI_QKV) {
        if (n0 >= 4096) {
            __syncthreads();  // all waves drained their DMA -> LDS reusable
            u16* Lb = (u16*)&lds[0][0];
            #pragma unroll
            for (int i = 0; i < 4; i++)
                #pragma unroll
                for (int r = 0; r < 4; r++) {
                    int rl = wm + i * 16 + q * 4 + r;
                    #pragma unroll
                    for (int j = 0; j < NJ; j++) {
                        int cl = wn + j * 16 + lr;
                        float v = acc[i][j][r] + bias[n0 + cl];
                        Lb[cl * 136 + rl] = f2bf(v);
                    }
                }
            __syncthreads();
            int b_ = m0 >> 11, nloc = m0 & 2047;
            u16* vt = aux + (size_t)b_ * 2048 * 2048 + (size_t)(n0 - 4096) * 2048 + nloc;
            int ec = t >> 4, nc = (t & 15) * 8;
            #pragma unroll
            for (int it = 0; it < 16; ++it) {
                int e = ec + it * 16;
                *(s16x8*)&vt[(size_t)e * 2048 + nc] = *(const s16x8*)&Lb[e * 136 + nc];
            }
            return;
        }
    }

    // ---- epilogue ----
    u16* Cb = (u16*)Cv + (size_t)z * ((EPI == EPI_PART) ? 0 : sC);
    float* Cf = (float*)Cv + (size_t)z * ((EPI == EPI_PART) ? sC : 0);
    #pragma unroll
    for (int i = 0; i < 4; i++) {
        #pragma unroll
        for (int r = 0; r < 4; r++) {
            int row = m0 + wm + i * 16 + q * 4 + r;
            float rs = 0.f;
            #pragma unroll
            for (int j = 0; j < NJ; j++) {
                int col = n0 + wn + j * 16 + lr;
                float v = acc[i][j][r];
                if (EPI == EPI_PART) {
                    Cf[(size_t)row * N + col] = v;
                } else if (EPI == EPI_TRIL) {
                    v = (col <= row) ? v : 0.f;
                    rs += v;
                    Cb[(size_t)row * N + col] = f2bf(v);
                } else if (EPI == EPI_DIV) {
                    float d = den[(size_t)z * sAux + row] + 1e-6f;
                    Cb[(size_t)row * N + col] = f2bf(v / d);
                } else {
                    v += bias[col];
                    if (EPI == EPI_QKV) {
                        v = (v > 0.f) ? (v + 1.f) : __expf(v);  // elu+1 (block fully in Q|K cols)
                    } else {  // EPI_GELU
                        float u = v * (0.7978845608f + 0.0356774081f * v * v);
                        u = fminf(u, 40.f);
                        float e = __expf(2.f * u);
                        v = v * __fdividef(e, e + 1.f);
                    }
                    Cb[(size_t)row * N + col] = f2bf(v);
                }
            }
            if (EPI == EPI_TRIL) {
                #pragma unroll
                for (int m = 1; m < 16; m <<= 1) rs += __shfl_xor(rs, m, 16);
                if (lr == 0) atomicAdd(&den[(size_t)z * sAux + row], rs);
            }
        }
    }
}

extern "C" void kernel_launch(void* const* d_in, const int* in_sizes, int n_in,
                              void* d_out, int out_size, void* d_ws, size_t ws_size,
                              hipStream_t stream) {
    const float* x    = (const float*)d_in[0];
    const float* q_w  = (const float*)d_in[1];
    const float* q_b  = (const float*)d_in[2];
    const float* k_w  = (const float*)d_in[3];
    const float* k_b  = (const float*)d_in[4];
    const float* v_w  = (const float*)d_in[5];
    const float* v_b  = (const float*)d_in[6];
    const float* o_w  = (const float*)d_in[7];
    const float* o_b  = (const float*)d_in[8];
    const float* ln1g = (const float*)d_in[9];
    const float* ln1b = (const float*)d_in[10];
    const float* ln2g = (const float*)d_in[11];
    const float* ln2b = (const float*)d_in[12];
    const float* w1   = (const float*)d_in[13];
    const float* b1   = (const float*)d_in[14];
    const float* w2   = (const float*)d_in[15];
    const float* b2   = (const float*)d_in[16];
    float* out = (float*)d_out;

    constexpr int Bb = 2, N = 2048, D = 1024, E = 2048, F = 4096;
    constexpr int BN = Bb * N;     // 4096
    constexpr int E3 = 3 * E;      // 6144

    char* ws = (char*)d_ws;
    size_t off = 0;
    auto alloc = [&](size_t bytes) -> void* {
        void* p = ws + off;
        off += (bytes + 255) & ~(size_t)255;
        return p;
    };
    u16*   qkvT = (u16*)alloc((size_t)E3 * D * 2);     // 12 MB
    u16*   oT   = (u16*)alloc((size_t)D * E * 2);      // 4 MB
    u16*   w1T  = (u16*)alloc((size_t)F * D * 2);      // 8 MB
    u16*   w2T  = (u16*)alloc((size_t)D * F * 2);      // 8 MB
    float* bcat = (float*)alloc((size_t)E3 * 4);
    u16*   xn   = (u16*)alloc((size_t)BN * D * 2);     // 8 MB (reused as xn2)
    u16*   QKV  = (u16*)alloc((size_t)BN * E3 * 2);    // 48 MB (reused: P, h)
    u16*   Vt   = (u16*)alloc((size_t)Bb * E * N * 2); // 16 MB (reused as x2 fp32)
    u16*   Amat = (u16*)alloc((size_t)Bb * N * N * 2); // 32 MB (reused as parts)
    float* den  = (float*)alloc((size_t)BN * 4);

    u16*   xn2 = xn;
    u16*   P   = QKV;                  // [BN,E] bf16
    u16*   h   = QKV + (size_t)8 * 1024 * 1024;  // [BN,F] bf16
    float* x2  = (float*)Vt;           // [BN,D] fp32
    float* pt0 = (float*)Amat;         // split-K partial 0
    float* pt1 = pt0 + (size_t)BN * D; // split-K partial 1

    dim3 blk(256);

    // ---- preproc: weight transposes + LN1 + bias pack + den zero ----
    preproc<<<dim3(4096, 7), blk, 0, stream>>>(
        q_w, k_w, v_w, o_w, w1, w2, qkvT, oT, w1T, w2T,
        x, ln1g, ln1b, xn, q_b, k_b, v_b, bcat, den);

    // ---- fused QKV projection: [BN,3E], elu+1 on Q,K cols; V cols -> Vt direct ----
    gemm2b<EPI_QKV, 256><<<dim3(E3 / 256, BN / 128), blk, 0, stream>>>(
        xn, qkvT, QKV, bcat, nullptr, Vt, BN, E3, D, D, D, 0, 0, 0, 0);

    // ---- A = tril(Q K^T) per batch, fused rowsum -> den ----
    gemm2b<EPI_TRIL, 128><<<dim3(N / 128, N / 128, Bb), blk, 0, stream>>>(
        QKV, QKV + E, Amat, nullptr, den, nullptr, N, N, E, E3, E3,
        (ll)N * E3, (ll)N * E3, (ll)N * N, (ll)N);

    // ---- P = (A @ V) / den (triangular kend) ----
    gemm2b<EPI_DIV, 128><<<dim3(E / 128, N / 128, Bb), blk, 0, stream>>>(
        Amat, Vt, P, nullptr, den, nullptr, N, E, N, N, N,
        (ll)N * N, (ll)E * N, (ll)N * E, (ll)N);

    // ---- split-K=2: parts = P @ o_w (fp32) ----
    gemm2b<EPI_PART, 128><<<dim3(D / 128, BN / 128, 2), blk, 0, stream>>>(
        P, oT, pt0, nullptr, nullptr, nullptr, BN, D, E / 2, E, E,
        (ll)(E / 2), (ll)(E / 2), (ll)BN * D, 0);

    // ---- x2 = x + p0 + p1 + o_b ; xn2 = LN2(x2) ----
    combine_ln<<<BN, blk, 0, stream>>>(x, pt0, pt1, o_b, ln2g, ln2b, x2, xn2);

    // ---- h = gelu(xn2 @ w1 + b1) ----
    gemm2b<EPI_GELU, 256><<<dim3(F / 256, BN / 128), blk, 0, stream>>>(
        xn2, w1T, h, b1, nullptr, nullptr, BN, F, D, D, D, 0, 0, 0, 0);

    // ---- split-K=2: parts = h @ w2 (fp32) ----
    gemm2b<EPI_PART, 128><<<dim3(D / 128, BN / 128, 2), blk, 0, stream>>>(
        h, w2T, pt0, nullptr, nullptr, nullptr, BN, D, F / 2, F, F,
        (ll)(F / 2), (ll)(F / 2), (ll)BN * D, 0);

    // ---- out = x2 + p0 + p1 + b2 ----
    combine_out<<<dim3(BN * D / 4 / 256), blk, 0, stream>>>(x2, pt0, pt1, b2, out);
}